// Round 1
// baseline (126.934 us; speedup 1.0000x reference)
//
#include <hip/hip_runtime.h>

// Problem constants (from reference)
constexpr int kB   = 16384;   // batch
constexpr int kNeg = 10;      // negatives per example
constexpr int kE   = 128;     // embedding dim
constexpr int kWavesPerBlock = 4;                 // 256 threads, 1 example per wave
constexpr int kBlocks = kB / kWavesPerBlock;      // 4096

__device__ __forceinline__ float log_sigmoid(float x) {
    // numerically stable: min(x,0) - log1p(exp(-|x|))
    return fminf(x, 0.0f) - log1pf(expf(-fabsf(x)));
}

__device__ __forceinline__ float dot4(float4 a, float4 b) {
    return a.x * b.x + a.y * b.y + a.z * b.z + a.w * b.w;
}

// One example per 64-lane wave:
//  - b is wave-uniform (forced to SGPR via readfirstlane) -> all 12 index
//    loads become s_load through the scalar cache (no redundant per-lane
//    vector loads).
//  - the 11 W_ctx rows + duplicated center are split across the two
//    32-lane halves: each lane issues 7 independent float4 gathers
//    (c + 6 rows), 28 data VGPRs instead of 48 -> fits 64-VGPR budget
//    -> __launch_bounds__(256,8) doubles occupancy to 32 waves/CU.
//  half0 rows: {x(cw), n0..n4}   half1 rows: {n5..n9, cw(dummy, discarded)}
__global__ __launch_bounds__(256, 8) void w2v_loss_kernel(
    const int*   __restrict__ input_word,
    const int*   __restrict__ context_word,
    const int*   __restrict__ noise_words,
    const float* __restrict__ W_in,
    const float* __restrict__ W_ctx,
    float*       __restrict__ partials)
{
    const int tid  = threadIdx.x;
    const int wave = tid >> 6;
    const int lane = tid & 63;
    const int half = lane >> 5;               // which 32-lane half
    const int l32  = lane & 31;               // lane within the half

    // wave-uniform example id, forced into an SGPR so the index loads scalarize
    const int b = __builtin_amdgcn_readfirstlane(blockIdx.x * kWavesPerBlock + wave);

    // All 12 indices via scalar loads (uniform addresses).
    const int iw = input_word[b];
    const int cw = context_word[b];
    int nw[kNeg];
    #pragma unroll
    for (int k = 0; k < kNeg; ++k)
        nw[k] = noise_words[b * kNeg + k];

    // Per-half row selection (cndmask on SGPR values -> cheap).
    int ridx[6];
    ridx[0] = half ? nw[5] : cw;
    #pragma unroll
    for (int j = 1; j <= 4; ++j)
        ridx[j] = half ? nw[5 + j] : nw[j - 1];
    ridx[5] = half ? cw : nw[4];              // half1 slot5 is a discarded dummy

    // 7 independent coalesced gathers (each half-wave reads a full 512B row).
    const float4 c = ((const float4*)(W_in + (size_t)iw * kE))[l32];
    float4 r[6];
    #pragma unroll
    for (int j = 0; j < 6; ++j)
        r[j] = ((const float4*)(W_ctx + (size_t)ridx[j] * kE))[l32];

    // Partial dots, then 5-step butterfly within each 32-lane half.
    float d[6];
    #pragma unroll
    for (int j = 0; j < 6; ++j)
        d[j] = dot4(c, r[j]);

    #pragma unroll
    for (int off = 16; off > 0; off >>= 1) {
        #pragma unroll
        for (int j = 0; j < 6; ++j)
            d[j] += __shfl_xor(d[j], off);
    }
    // Every lane of a half now holds its half's 6 full dot products.

    // Distribute the log_sigmoid evaluations across lanes 0..5 of each half
    // (static selection chain -- no runtime-indexed register array).
    float v = d[0];
    #pragma unroll
    for (int j = 1; j < 6; ++j)
        v = (l32 == j) ? d[j] : v;
    const bool isPos = (half == 0) && (l32 == 0);   // half0 slot0 = positive score
    v = isPos ? v : -v;                              // negatives use logsig(-dot)
    const bool active = half ? (l32 < 5) : (l32 < 6); // half1 slot5 discarded
    float s = active ? log_sigmoid(v) : 0.0f;

    // Sum 11 terms: 5 steps within-half, 1 step across halves.
    #pragma unroll
    for (int off = 16; off > 0; off >>= 1)
        s += __shfl_xor(s, off);
    s += __shfl_xor(s, 32);

    __shared__ float smem[kWavesPerBlock];
    if (lane == 0) smem[wave] = s;
    __syncthreads();
    if (tid == 0)
        partials[blockIdx.x] = smem[0] + smem[1] + smem[2] + smem[3];
}

__global__ __launch_bounds__(256) void w2v_reduce_kernel(
    const float* __restrict__ partials,
    float*       __restrict__ out)
{
    float acc = 0.0f;
    for (int i = threadIdx.x; i < kBlocks; i += 256)
        acc += partials[i];

    #pragma unroll
    for (int off = 32; off > 0; off >>= 1)
        acc += __shfl_xor(acc, off);

    __shared__ float smem[4];
    const int lane = threadIdx.x & 63;
    const int wave = threadIdx.x >> 6;
    if (lane == 0) smem[wave] = acc;
    __syncthreads();
    if (threadIdx.x == 0) {
        const float total = smem[0] + smem[1] + smem[2] + smem[3];
        out[0] = -total / (float)kB;
    }
}

extern "C" void kernel_launch(void* const* d_in, const int* in_sizes, int n_in,
                              void* d_out, int out_size, void* d_ws, size_t ws_size,
                              hipStream_t stream) {
    const int*   input_word   = (const int*)d_in[0];
    const int*   context_word = (const int*)d_in[1];
    const int*   noise_words  = (const int*)d_in[2];
    const float* W_in         = (const float*)d_in[3];
    const float* W_ctx        = (const float*)d_in[4];
    float*       out          = (float*)d_out;
    float*       partials     = (float*)d_ws;   // kBlocks floats (16 KiB)

    w2v_loss_kernel<<<kBlocks, 256, 0, stream>>>(
        input_word, context_word, noise_words, W_in, W_ctx, partials);
    w2v_reduce_kernel<<<1, 256, 0, stream>>>(partials, out);
}